// Round 3
// baseline (830.063 us; speedup 1.0000x reference)
//
#include <hip/hip_runtime.h>
#include <hip/hip_bf16.h>
#include <math.h>

#define H 128
#define KP1 288      // padded K for GEMM1 (258 -> 288 = 9 k-blocks of 32)
#define TEB 64       // edges per block
#define TN 32        // nodes per block (node kernel)

typedef __attribute__((ext_vector_type(8))) short bf16x8;
typedef __attribute__((ext_vector_type(4))) float f32x4;

__device__ __forceinline__ float silu_f(float x) { return x / (1.0f + __expf(-x)); }

__device__ __forceinline__ unsigned short f2bf(float f) {
    unsigned int u = __float_as_uint(f);
    unsigned int r = u + 0x7FFFu + ((u >> 16) & 1u);
    return (unsigned short)(r >> 16);
}

// -------------------- weight prep: W[K][128] fp32 -> Wt[128][Kp] bf16 ------
__global__ void prep_wt(const float* __restrict__ W, unsigned short* __restrict__ Wt,
                        int K, int Kp) {
    int n = blockIdx.y;
    int k = blockIdx.x * 256 + threadIdx.x;
    if (k < Kp) Wt[(size_t)n * Kp + k] = (k < K) ? f2bf(W[(size_t)k * H + n]) : (unsigned short)0;
}

// -------------------- CSR build --------------------
__global__ void hist_kernel(const int* __restrict__ ei, int* __restrict__ deg, int E) {
    int e = blockIdx.x * 256 + threadIdx.x;
    if (e < E) atomicAdd(&deg[ei[e]], 1);
}

// single-block 3-phase exclusive scan: deg[N] -> offs[N+1], cursor[N]
__global__ void scan_kernel(const int* __restrict__ deg, int* __restrict__ offs,
                            int* __restrict__ cursor, int N) {
    __shared__ int tsum[256];
    const int t = threadIdx.x;
    const int CH = (N + 255) / 256;
    int lo = t * CH, hi = lo + CH; if (hi > N) hi = N; if (lo > N) lo = N;
    int s = 0;
    for (int i = lo; i < hi; ++i) s += deg[i];
    tsum[t] = s;
    __syncthreads();
    int v = s;
    for (int off = 1; off < 256; off <<= 1) {
        int u = (t >= off) ? tsum[t - off] : 0;
        __syncthreads();
        v += u; tsum[t] = v;
        __syncthreads();
    }
    int run = v - s;   // exclusive prefix of this thread's chunk
    for (int i = lo; i < hi; ++i) {
        offs[i] = run; cursor[i] = run; run += deg[i];
    }
    if (t == 255) offs[N] = run;
}

__global__ void scatter_kernel(const int* __restrict__ ei, int* __restrict__ cursor,
                               int* __restrict__ eids, int E) {
    int e = blockIdx.x * 256 + threadIdx.x;
    if (e < E) {
        int p = atomicAdd(&cursor[ei[e]], 1);
        eids[p] = e;
    }
}

// -------------------- edge kernel (MFMA bf16) --------------------
#define SMEM_BYTES (36864 + 64 * 3 * 4 + 64 * 4)

__global__ __launch_bounds__(256) void edge_kernel(
    const float* __restrict__ h, const int* __restrict__ ei,
    const float* __restrict__ coord, const float* __restrict__ eattr,
    const unsigned short* __restrict__ eW1t,
    const float* __restrict__ eb1, const float* __restrict__ eg1, const float* __restrict__ ebe1,
    const unsigned short* __restrict__ eW2t,
    const float* __restrict__ eb2, const float* __restrict__ eg2, const float* __restrict__ ebe2,
    const unsigned short* __restrict__ cW1t,
    const float* __restrict__ cb1, const float* __restrict__ cg1, const float* __restrict__ cbe1,
    const float* __restrict__ cW2,
    unsigned short* __restrict__ efbuf, float* __restrict__ agg,
    float* __restrict__ coord_out, int E, int use_csr)
{
    __shared__ char smem[SMEM_BYTES];
    unsigned short* A1    = (unsigned short*)smem;
    float*          cd_s  = (float*)(smem + 36864);
    int*            row_s = (int*)(smem + 36864 + 64 * 3 * 4);

    const int t    = threadIdx.x;
    const int lane = t & 63, wave = t >> 6;
    const int l15  = lane & 15, quad = lane >> 4;

    // ---- stage A1: 4 threads per edge; bf16 convert on the fly ----
    {
        const int m = t >> 2, part = t & 3;
        int ge  = blockIdx.x * TEB + m;
        int gec = (ge < E) ? ge : 0;
        int row = ei[gec], colv = ei[E + gec];
        const float* src = ((part < 2) ? (h + (size_t)row * H) : (h + (size_t)colv * H))
                           + (part & 1) * 64;
        const int baseoct = part * 8;
        #pragma unroll
        for (int o = 0; o < 8; ++o) {
            float4 f0 = ((const float4*)src)[2 * o];
            float4 f1 = ((const float4*)src)[2 * o + 1];
            union { bf16x8 v; unsigned short u[8]; } pk;
            pk.u[0] = f2bf(f0.x); pk.u[1] = f2bf(f0.y); pk.u[2] = f2bf(f0.z); pk.u[3] = f2bf(f0.w);
            pk.u[4] = f2bf(f1.x); pk.u[5] = f2bf(f1.y); pk.u[6] = f2bf(f1.z); pk.u[7] = f2bf(f1.w);
            *(bf16x8*)&A1[((baseoct + o) * TEB + m) * 8] = pk.v;
        }
        if (part == 0) {
            row_s[m] = row;
            float dx = coord[row * 3 + 0] - coord[colv * 3 + 0];
            float dy = coord[row * 3 + 1] - coord[colv * 3 + 1];
            float dz = coord[row * 3 + 2] - coord[colv * 3 + 2];
            float radial = dx * dx + dy * dy + dz * dz;
            float inv = 1.0f / (sqrtf(radial + 1e-8f) + 1.0f);
            cd_s[m * 3 + 0] = dx * inv;
            cd_s[m * 3 + 1] = dy * inv;
            cd_s[m * 3 + 2] = dz * inv;
            union { bf16x8 v; unsigned short u[8]; } pk;
            #pragma unroll
            for (int i = 0; i < 8; ++i) pk.u[i] = 0;
            pk.u[0] = f2bf(radial);
            pk.u[1] = f2bf((ge < E) ? eattr[ge] : 0.0f);
            *(bf16x8*)&A1[(32 * TEB + m) * 8] = pk.v;
            #pragma unroll
            for (int i = 0; i < 8; ++i) pk.u[i] = 0;
            *(bf16x8*)&A1[(33 * TEB + m) * 8] = pk.v;
            *(bf16x8*)&A1[(34 * TEB + m) * 8] = pk.v;
            *(bf16x8*)&A1[(35 * TEB + m) * 8] = pk.v;
        }
    }
    __syncthreads();

    const int mrow = wave * 16 + l15;
    const int col  = l15;

    f32x4 acc[8];
    #pragma unroll
    for (int nt = 0; nt < 8; ++nt) acc[nt] = (f32x4){0.f, 0.f, 0.f, 0.f};

    // ---- GEMM1: [64x288] @ eW1t ----
    for (int kb = 0; kb < 9; ++kb) {
        bf16x8 af = *(const bf16x8*)&A1[((kb * 4 + quad) * TEB + mrow) * 8];
        const unsigned short* bp = eW1t + (size_t)l15 * KP1 + kb * 32 + quad * 8;
        #pragma unroll
        for (int nt = 0; nt < 8; ++nt) {
            bf16x8 bf = *(const bf16x8*)(bp + (size_t)nt * 16 * KP1);
            acc[nt] = __builtin_amdgcn_mfma_f32_16x16x32_bf16(af, bf, acc[nt], 0, 0, 0);
        }
    }
    __syncthreads();

    unsigned short* A2w = (unsigned short*)smem + wave * 2048;
    unsigned short* A3w = (unsigned short*)smem + 8192 + wave * 2048;

    // ---- epilogue 1: bias + LN + SiLU -> A2 (bf16) ----
    {
        float s[4] = {0, 0, 0, 0}, ss[4] = {0, 0, 0, 0};
        #pragma unroll
        for (int nt = 0; nt < 8; ++nt) {
            float b = eb1[nt * 16 + col];
            #pragma unroll
            for (int r = 0; r < 4; ++r) {
                float x = acc[nt][r] + b;
                acc[nt][r] = x;
                s[r] += x; ss[r] += x * x;
            }
        }
        #pragma unroll
        for (int msk = 1; msk <= 8; msk <<= 1) {
            #pragma unroll
            for (int r = 0; r < 4; ++r) {
                s[r]  += __shfl_xor(s[r],  msk, 64);
                ss[r] += __shfl_xor(ss[r], msk, 64);
            }
        }
        float mu[4], rstd[4];
        #pragma unroll
        for (int r = 0; r < 4; ++r) {
            mu[r] = s[r] * (1.0f / 128.0f);
            float var = ss[r] * (1.0f / 128.0f) - mu[r] * mu[r];
            rstd[r] = rsqrtf(var + 1e-5f);
        }
        #pragma unroll
        for (int nt = 0; nt < 8; ++nt) {
            float g = eg1[nt * 16 + col], be = ebe1[nt * 16 + col];
            int oct = nt * 2 + (l15 >> 3), j = l15 & 7;
            #pragma unroll
            for (int r = 0; r < 4; ++r) {
                float y = silu_f((acc[nt][r] - mu[r]) * rstd[r] * g + be);
                A2w[((oct * 16 + (quad * 4 + r)) * 8) + j] = f2bf(y);
            }
        }
    }

    // ---- GEMM2: [16x128] @ eW2t ----
    #pragma unroll
    for (int nt = 0; nt < 8; ++nt) acc[nt] = (f32x4){0.f, 0.f, 0.f, 0.f};
    for (int kb = 0; kb < 4; ++kb) {
        bf16x8 af = *(const bf16x8*)&A2w[((kb * 4 + quad) * 16 + l15) * 8];
        const unsigned short* bp = eW2t + (size_t)l15 * H + kb * 32 + quad * 8;
        #pragma unroll
        for (int nt = 0; nt < 8; ++nt) {
            bf16x8 bf = *(const bf16x8*)(bp + (size_t)nt * 16 * H);
            acc[nt] = __builtin_amdgcn_mfma_f32_16x16x32_bf16(af, bf, acc[nt], 0, 0, 0);
        }
    }

    // ---- epilogue 2: bias + LN + SiLU = edge_feat; store ef (CSR) or atomics ----
    {
        float s[4] = {0, 0, 0, 0}, ss[4] = {0, 0, 0, 0};
        #pragma unroll
        for (int nt = 0; nt < 8; ++nt) {
            float b = eb2[nt * 16 + col];
            #pragma unroll
            for (int r = 0; r < 4; ++r) {
                float x = acc[nt][r] + b;
                acc[nt][r] = x;
                s[r] += x; ss[r] += x * x;
            }
        }
        #pragma unroll
        for (int msk = 1; msk <= 8; msk <<= 1) {
            #pragma unroll
            for (int r = 0; r < 4; ++r) {
                s[r]  += __shfl_xor(s[r],  msk, 64);
                ss[r] += __shfl_xor(ss[r], msk, 64);
            }
        }
        float mu[4], rstd[4];
        #pragma unroll
        for (int r = 0; r < 4; ++r) {
            mu[r] = s[r] * (1.0f / 128.0f);
            float var = ss[r] * (1.0f / 128.0f) - mu[r] * mu[r];
            rstd[r] = rsqrtf(var + 1e-5f);
        }
        #pragma unroll
        for (int nt = 0; nt < 8; ++nt) {
            float g = eg2[nt * 16 + col], be = ebe2[nt * 16 + col];
            int oct = nt * 2 + (l15 >> 3), j = l15 & 7;
            #pragma unroll
            for (int r = 0; r < 4; ++r) {
                float ef = silu_f((acc[nt][r] - mu[r]) * rstd[r] * g + be);
                unsigned int b16 = f2bf(ef);
                A3w[((oct * 16 + (quad * 4 + r)) * 8) + j] = (unsigned short)b16;
                int m  = wave * 16 + quad * 4 + r;
                int ge = blockIdx.x * TEB + m;
                if (use_csr) {
                    // pair even/odd l15 lanes -> one 4B store of 2 bf16
                    unsigned int other = (unsigned int)__shfl_xor((int)b16, 1, 64);
                    if (!(l15 & 1) && ge < E) {
                        *(unsigned int*)(efbuf + (size_t)ge * H + nt * 16 + l15)
                            = (b16 & 0xFFFFu) | (other << 16);
                    }
                } else {
                    if (ge < E)
                        atomicAdd(&agg[(size_t)row_s[m] * H + nt * 16 + col], ef);
                }
            }
        }
    }

    // ---- GEMM3: edge_feat @ cW1t ----
    #pragma unroll
    for (int nt = 0; nt < 8; ++nt) acc[nt] = (f32x4){0.f, 0.f, 0.f, 0.f};
    for (int kb = 0; kb < 4; ++kb) {
        bf16x8 af = *(const bf16x8*)&A3w[((kb * 4 + quad) * 16 + l15) * 8];
        const unsigned short* bp = cW1t + (size_t)l15 * H + kb * 32 + quad * 8;
        #pragma unroll
        for (int nt = 0; nt < 8; ++nt) {
            bf16x8 bf = *(const bf16x8*)(bp + (size_t)nt * 16 * H);
            acc[nt] = __builtin_amdgcn_mfma_f32_16x16x32_bf16(af, bf, acc[nt], 0, 0, 0);
        }
    }

    // ---- epilogue 3: bias + LN + SiLU, dot cW2 -> cm; coord atomics ----
    {
        float s[4] = {0, 0, 0, 0}, ss[4] = {0, 0, 0, 0};
        #pragma unroll
        for (int nt = 0; nt < 8; ++nt) {
            float b = cb1[nt * 16 + col];
            #pragma unroll
            for (int r = 0; r < 4; ++r) {
                float x = acc[nt][r] + b;
                acc[nt][r] = x;
                s[r] += x; ss[r] += x * x;
            }
        }
        #pragma unroll
        for (int msk = 1; msk <= 8; msk <<= 1) {
            #pragma unroll
            for (int r = 0; r < 4; ++r) {
                s[r]  += __shfl_xor(s[r],  msk, 64);
                ss[r] += __shfl_xor(ss[r], msk, 64);
            }
        }
        float cm[4] = {0, 0, 0, 0};
        float mu[4], rstd[4];
        #pragma unroll
        for (int r = 0; r < 4; ++r) {
            mu[r] = s[r] * (1.0f / 128.0f);
            float var = ss[r] * (1.0f / 128.0f) - mu[r] * mu[r];
            rstd[r] = rsqrtf(var + 1e-5f);
        }
        #pragma unroll
        for (int nt = 0; nt < 8; ++nt) {
            float g = cg1[nt * 16 + col], be = cbe1[nt * 16 + col];
            float w2 = cW2[nt * 16 + col];
            #pragma unroll
            for (int r = 0; r < 4; ++r) {
                float p = silu_f((acc[nt][r] - mu[r]) * rstd[r] * g + be);
                cm[r] += p * w2;
            }
        }
        #pragma unroll
        for (int msk = 1; msk <= 8; msk <<= 1) {
            #pragma unroll
            for (int r = 0; r < 4; ++r) cm[r] += __shfl_xor(cm[r], msk, 64);
        }
        if (l15 < 3) {
            #pragma unroll
            for (int r = 0; r < 4; ++r) {
                int m  = wave * 16 + quad * 4 + r;
                int ge = blockIdx.x * TEB + m;
                if (ge < E)
                    atomicAdd(&coord_out[(size_t)row_s[m] * 3 + l15],
                              cd_s[m * 3 + l15] * cm[r]);
            }
        }
    }
}

// -------------------- node kernel: gather (CSR) or read agg, then fp32 MLP ------
__global__ __launch_bounds__(256) void node_kernel(
    const float* __restrict__ h,
    const unsigned short* __restrict__ efbuf,
    const int* __restrict__ offs, const int* __restrict__ eids,
    const float* __restrict__ agg,
    const float* __restrict__ nW1, const float* __restrict__ nb1,
    const float* __restrict__ ng1, const float* __restrict__ nbe1,
    const float* __restrict__ nW2, const float* __restrict__ nb2,
    float* __restrict__ out, int N, int use_csr)
{
    __shared__ float nin_s[TN * 256];
    __shared__ float buf_s[TN * H];

    const int t = threadIdx.x;
    const int g = t >> 3, j = t & 7;   // 8 threads per node

    // ---- stage h ----
    {
        int gn = blockIdx.x * TN + g;
        int gnc = (gn < N) ? gn : (N - 1);
        const float4* hr = (const float4*)(h + (size_t)gnc * H);
        #pragma unroll
        for (int i = 0; i < 4; ++i)
            *(float4*)&nin_s[g * 256 + 4 * (j + 8 * i)] = hr[j + 8 * i];
    }

    // ---- stage agg: gather-sum (CSR) or load precomputed ----
    if (use_csr) {
        int gn = blockIdx.x * TN + g;
        float accv[16];
        #pragma unroll
        for (int k = 0; k < 16; ++k) accv[k] = 0.0f;
        if (gn < N) {
            int p0 = offs[gn], p1 = offs[gn + 1];
            for (int p = p0; p < p1; ++p) {
                int e = eids[p];
                const uint4* src = (const uint4*)(efbuf + (size_t)e * H + j * 16);
                uint4 u0 = src[0], u1 = src[1];
                accv[0]  += __uint_as_float(u0.x << 16);
                accv[1]  += __uint_as_float(u0.x & 0xFFFF0000u);
                accv[2]  += __uint_as_float(u0.y << 16);
                accv[3]  += __uint_as_float(u0.y & 0xFFFF0000u);
                accv[4]  += __uint_as_float(u0.z << 16);
                accv[5]  += __uint_as_float(u0.z & 0xFFFF0000u);
                accv[6]  += __uint_as_float(u0.w << 16);
                accv[7]  += __uint_as_float(u0.w & 0xFFFF0000u);
                accv[8]  += __uint_as_float(u1.x << 16);
                accv[9]  += __uint_as_float(u1.x & 0xFFFF0000u);
                accv[10] += __uint_as_float(u1.y << 16);
                accv[11] += __uint_as_float(u1.y & 0xFFFF0000u);
                accv[12] += __uint_as_float(u1.z << 16);
                accv[13] += __uint_as_float(u1.z & 0xFFFF0000u);
                accv[14] += __uint_as_float(u1.w << 16);
                accv[15] += __uint_as_float(u1.w & 0xFFFF0000u);
            }
        }
        #pragma unroll
        for (int k = 0; k < 16; ++k) nin_s[g * 256 + H + j * 16 + k] = accv[k];
    } else {
        int gn = blockIdx.x * TN + g;
        int gnc = (gn < N) ? gn : (N - 1);
        const float4* ar = (const float4*)(agg + (size_t)gnc * H);
        #pragma unroll
        for (int i = 0; i < 4; ++i)
            *(float4*)&nin_s[g * 256 + H + 4 * (j + 8 * i)] = ar[j + 8 * i];
    }
    __syncthreads();

    const int cc = t & 31, ceb = t >> 5;

    float acc[4][4];
    #pragma unroll
    for (int q = 0; q < 4; ++q)
        for (int jj = 0; jj < 4; ++jj) acc[q][jj] = 0.0f;

    #pragma unroll 2
    for (int k = 0; k < 2 * H; ++k) {
        float4 wv = *(const float4*)(nW1 + (size_t)k * H + 4 * cc);
        #pragma unroll
        for (int q = 0; q < 4; ++q) {
            float a = nin_s[(ceb + 8 * q) * 256 + k];
            acc[q][0] += a * wv.x; acc[q][1] += a * wv.y;
            acc[q][2] += a * wv.z; acc[q][3] += a * wv.w;
        }
    }

    {
        float4 bv  = *(const float4*)(nb1 + 4 * cc);
        float4 gv  = *(const float4*)(ng1 + 4 * cc);
        float4 bev = *(const float4*)(nbe1 + 4 * cc);
        #pragma unroll
        for (int q = 0; q < 4; ++q) {
            float x0 = acc[q][0] + bv.x, x1 = acc[q][1] + bv.y;
            float x2 = acc[q][2] + bv.z, x3 = acc[q][3] + bv.w;
            float s  = x0 + x1 + x2 + x3;
            float ss = x0 * x0 + x1 * x1 + x2 * x2 + x3 * x3;
            #pragma unroll
            for (int m = 1; m <= 16; m <<= 1) {
                s  += __shfl_xor(s, m, 64);
                ss += __shfl_xor(ss, m, 64);
            }
            float mu   = s * (1.0f / 128.0f);
            float var  = ss * (1.0f / 128.0f) - mu * mu;
            float rstd = rsqrtf(var + 1e-5f);
            float* dst = &buf_s[(ceb + 8 * q) * H + 4 * cc];
            dst[0] = silu_f((x0 - mu) * rstd * gv.x + bev.x);
            dst[1] = silu_f((x1 - mu) * rstd * gv.y + bev.y);
            dst[2] = silu_f((x2 - mu) * rstd * gv.z + bev.z);
            dst[3] = silu_f((x3 - mu) * rstd * gv.w + bev.w);
        }
    }
    __syncthreads();

    float a2[4][4];
    #pragma unroll
    for (int q = 0; q < 4; ++q)
        for (int jj = 0; jj < 4; ++jj) a2[q][jj] = 0.0f;

    #pragma unroll 4
    for (int k = 0; k < H; ++k) {
        float4 wv = *(const float4*)(nW2 + (size_t)k * H + 4 * cc);
        #pragma unroll
        for (int q = 0; q < 4; ++q) {
            float a = buf_s[(ceb + 8 * q) * H + k];
            a2[q][0] += a * wv.x; a2[q][1] += a * wv.y;
            a2[q][2] += a * wv.z; a2[q][3] += a * wv.w;
        }
    }

    {
        float4 bv = *(const float4*)(nb2 + 4 * cc);
        #pragma unroll
        for (int q = 0; q < 4; ++q) {
            int gn = blockIdx.x * TN + (ceb + 8 * q);
            if (gn < N) {
                float4 hv = *(const float4*)(h + (size_t)gn * H + 4 * cc);
                float4 o;
                o.x = a2[q][0] + bv.x + hv.x;
                o.y = a2[q][1] + bv.y + hv.y;
                o.z = a2[q][2] + bv.z + hv.z;
                o.w = a2[q][3] + bv.w + hv.w;
                *(float4*)(out + (size_t)gn * H + 4 * cc) = o;
            }
        }
    }
}

// -------------------- launch --------------------
extern "C" void kernel_launch(void* const* d_in, const int* in_sizes, int n_in,
                              void* d_out, int out_size, void* d_ws, size_t ws_size,
                              hipStream_t stream) {
    const float* h     = (const float*)d_in[0];
    const int*   ei    = (const int*)d_in[1];
    const float* coord = (const float*)d_in[2];
    const float* eattr = (const float*)d_in[3];
    const float* eW1   = (const float*)d_in[4];
    const float* eb1   = (const float*)d_in[5];
    const float* eg1   = (const float*)d_in[6];
    const float* ebe1  = (const float*)d_in[7];
    const float* eW2   = (const float*)d_in[8];
    const float* eb2   = (const float*)d_in[9];
    const float* eg2   = (const float*)d_in[10];
    const float* ebe2  = (const float*)d_in[11];
    const float* nW1   = (const float*)d_in[12];
    const float* nb1   = (const float*)d_in[13];
    const float* ng1   = (const float*)d_in[14];
    const float* nbe1  = (const float*)d_in[15];
    const float* nW2   = (const float*)d_in[16];
    const float* nb2   = (const float*)d_in[17];
    const float* cW1   = (const float*)d_in[18];
    const float* cb1   = (const float*)d_in[19];
    const float* cg1   = (const float*)d_in[20];
    const float* cbe1  = (const float*)d_in[21];
    const float* cW2   = (const float*)d_in[22];

    const int N = in_sizes[0] / H;
    const int E = in_sizes[1] / 2;

    float* out       = (float*)d_out;
    float* coord_out = out + (size_t)N * H;

    // ---- workspace layout: try CSR, fall back to atomic-agg if ws too small ----
    char* ws = (char*)d_ws;
    size_t need_csr = 0;
    unsigned short* efbuf = (unsigned short*)(ws);            need_csr += (size_t)E * H * 2;
    unsigned short* eW1t  = (unsigned short*)(ws + need_csr); need_csr += (size_t)H * KP1 * 2;
    unsigned short* eW2t  = (unsigned short*)(ws + need_csr); need_csr += (size_t)H * H * 2;
    unsigned short* cW1t  = (unsigned short*)(ws + need_csr); need_csr += (size_t)H * H * 2;
    int* deg    = (int*)(ws + need_csr); need_csr += (size_t)N * 4;
    int* cursor = (int*)(ws + need_csr); need_csr += (size_t)N * 4;
    int* offs   = (int*)(ws + need_csr); need_csr += (size_t)(N + 1) * 4;
    int* eids   = (int*)(ws + need_csr); need_csr += (size_t)E * 4;

    const int use_csr = (need_csr <= ws_size) ? 1 : 0;

    float* agg = nullptr;
    if (!use_csr) {
        size_t o = 0;
        agg  = (float*)(ws);                         o += (size_t)N * H * 4;
        eW1t = (unsigned short*)(ws + o);            o += (size_t)H * KP1 * 2;
        eW2t = (unsigned short*)(ws + o);            o += (size_t)H * H * 2;
        cW1t = (unsigned short*)(ws + o);
        efbuf = nullptr; deg = cursor = offs = eids = nullptr;
        hipMemsetAsync(agg, 0, (size_t)N * H * sizeof(float), stream);
    } else {
        hipMemsetAsync(deg, 0, (size_t)N * sizeof(int), stream);
    }

    hipMemcpyAsync(coord_out, coord, (size_t)N * 3 * sizeof(float),
                   hipMemcpyDeviceToDevice, stream);

    prep_wt<<<dim3((KP1 + 255) / 256, H), 256, 0, stream>>>(eW1, eW1t, 258, KP1);
    prep_wt<<<dim3(1, H), 256, 0, stream>>>(eW2, eW2t, H, H);
    prep_wt<<<dim3(1, H), 256, 0, stream>>>(cW1, cW1t, H, H);

    if (use_csr) {
        hist_kernel<<<(E + 255) / 256, 256, 0, stream>>>(ei, deg, E);
        scan_kernel<<<1, 256, 0, stream>>>(deg, offs, cursor, N);
        scatter_kernel<<<(E + 255) / 256, 256, 0, stream>>>(ei, cursor, eids, E);
    }

    edge_kernel<<<(E + TEB - 1) / TEB, 256, 0, stream>>>(
        h, ei, coord, eattr,
        eW1t, eb1, eg1, ebe1,
        eW2t, eb2, eg2, ebe2,
        cW1t, cb1, cg1, cbe1, cW2,
        efbuf, agg, coord_out, E, use_csr);

    node_kernel<<<(N + TN - 1) / TN, 256, 0, stream>>>(
        h, efbuf, offs, eids, agg,
        nW1, nb1, ng1, nbe1, nW2, nb2, out, N, use_csr);
}

// Round 4
// 639.366 us; speedup vs baseline: 1.2983x; 1.2983x over previous
//
#include <hip/hip_runtime.h>
#include <math.h>

#define H 128
#define KE 256      // MFMA K for edge GEMM1 (k=256,257 handled as fp32 rank-1 update)
#define KN 256      // node GEMM1 K (2H)

typedef __attribute__((ext_vector_type(8))) short bf16x8;
typedef __attribute__((ext_vector_type(4))) float f32x4;

__device__ __forceinline__ float silu_f(float x) { return x / (1.0f + __expf(-x)); }

__device__ __forceinline__ unsigned short f2bf(float f) {
    unsigned int u = __float_as_uint(f);
    unsigned int r = u + 0x7FFFu + ((u >> 16) & 1u);
    return (unsigned short)(r >> 16);
}

// -------------------- prep: h fp32 -> bf16 --------------------
__global__ void prep_h(const float* __restrict__ x, unsigned short* __restrict__ y, int n) {
    int i = blockIdx.x * 256 + threadIdx.x;
    if (i < n) y[i] = f2bf(x[i]);
}

// -------------------- prep: W[K][128] fp32 -> Wt[128][Kt] bf16 (k<Kt rows) ------
__global__ void prep_wt(const float* __restrict__ W, unsigned short* __restrict__ Wt, int Kt) {
    int n = blockIdx.y;
    int k = blockIdx.x * 256 + threadIdx.x;
    if (k < Kt) Wt[(size_t)n * Kt + k] = f2bf(W[(size_t)k * H + n]);
}

// -------------------- shared epilogue: bias + LN + SiLU; result in acc and LDS ----
__device__ __forceinline__ void ln_silu_store(
    f32x4* acc, const float* __restrict__ bias, const float* __restrict__ g,
    const float* __restrict__ be, unsigned short* dstA, int l15, int quad)
{
    float s[4] = {0, 0, 0, 0}, ss[4] = {0, 0, 0, 0};
    #pragma unroll
    for (int nt = 0; nt < 8; ++nt) {
        float b = bias[nt * 16 + l15];
        #pragma unroll
        for (int r = 0; r < 4; ++r) {
            float x = acc[nt][r] + b;
            acc[nt][r] = x;
            s[r] += x; ss[r] += x * x;
        }
    }
    #pragma unroll
    for (int m = 1; m <= 8; m <<= 1) {
        #pragma unroll
        for (int r = 0; r < 4; ++r) {
            s[r]  += __shfl_xor(s[r],  m, 64);
            ss[r] += __shfl_xor(ss[r], m, 64);
        }
    }
    #pragma unroll
    for (int r = 0; r < 4; ++r) {
        float mu   = s[r] * (1.0f / 128.0f);
        float var  = ss[r] * (1.0f / 128.0f) - mu * mu;
        s[r]  = mu;
        ss[r] = rsqrtf(var + 1e-5f);
    }
    #pragma unroll
    for (int nt = 0; nt < 8; ++nt) {
        float gg = g[nt * 16 + l15], bb = be[nt * 16 + l15];
        int oct = nt * 2 + (l15 >> 3), j = l15 & 7;
        #pragma unroll
        for (int r = 0; r < 4; ++r) {
            float y = silu_f((acc[nt][r] - s[r]) * ss[r] * gg + bb);
            acc[nt][r] = y;
            dstA[(oct * 16 + quad * 4 + r) * 8 + j] = f2bf(y);
        }
    }
}

// -------------------- edge kernel: 1 wave, 16 edges, barrier-free --------------------
__global__ __launch_bounds__(64, 5) void edge_kernel(
    const unsigned short* __restrict__ hb, const int* __restrict__ ei,
    const float* __restrict__ coord, const float* __restrict__ eattr,
    const unsigned short* __restrict__ eW1t, const float* __restrict__ eW1,
    const float* __restrict__ eb1, const float* __restrict__ eg1, const float* __restrict__ ebe1,
    const unsigned short* __restrict__ eW2t,
    const float* __restrict__ eb2, const float* __restrict__ eg2, const float* __restrict__ ebe2,
    const unsigned short* __restrict__ cW1t,
    const float* __restrict__ cb1, const float* __restrict__ cg1, const float* __restrict__ cbe1,
    const float* __restrict__ cW2,
    float* __restrict__ agg, float* __restrict__ coord_out, int E)
{
    __shared__ unsigned short A[32 * 16 * 8];   // 8192 B: [oct<32][m<16][8]

    const int lane = threadIdx.x;
    const int l15 = lane & 15, quad = lane >> 4;
    const int me = lane >> 2, part = lane & 3;
    const int ge0 = blockIdx.x * 16;

    // ---- stage: 4 lanes/edge, 8 x 16B bf16 loads each, no conversion ----
    int ge  = ge0 + me;
    int gec = (ge < E) ? ge : (E - 1);
    int row = ei[gec], col = ei[E + gec];
    {
        const unsigned short* src =
            ((part < 2) ? (hb + (size_t)row * H) : (hb + (size_t)col * H)) + (part & 1) * 64;
        const int oct0 = part * 8;
        #pragma unroll
        for (int c = 0; c < 8; ++c)
            *(uint4*)&A[((oct0 + c) * 16 + me) * 8] = *(const uint4*)(src + c * 8);
    }
    float radial_reg = 0.f, ea_reg = 0.f, cdx = 0.f, cdy = 0.f, cdz = 0.f;
    if (part == 0) {
        float dx = coord[row * 3 + 0] - coord[col * 3 + 0];
        float dy = coord[row * 3 + 1] - coord[col * 3 + 1];
        float dz = coord[row * 3 + 2] - coord[col * 3 + 2];
        radial_reg = dx * dx + dy * dy + dz * dz;
        float inv = 1.0f / (sqrtf(radial_reg + 1e-8f) + 1.0f);
        cdx = dx * inv; cdy = dy * inv; cdz = dz * inv;
        ea_reg = eattr[gec];
    }

    f32x4 acc[8];
    #pragma unroll
    for (int nt = 0; nt < 8; ++nt) acc[nt] = (f32x4){0.f, 0.f, 0.f, 0.f};

    // ---- GEMM1: [16x256] @ eW1t[128][256] ----
    for (int kb = 0; kb < 8; ++kb) {
        bf16x8 af = *(const bf16x8*)&A[((kb * 4 + quad) * 16 + l15) * 8];
        const unsigned short* bp = eW1t + (size_t)l15 * KE + kb * 32 + quad * 8;
        #pragma unroll
        for (int nt = 0; nt < 8; ++nt) {
            bf16x8 bf = *(const bf16x8*)(bp + (size_t)nt * 16 * KE);
            acc[nt] = __builtin_amdgcn_mfma_f32_16x16x32_bf16(af, bf, acc[nt], 0, 0, 0);
        }
    }

    // ---- rank-1 fp32 update: k=256 (radial), k=257 (eattr) ----
    float rad_r[4], ea_r[4];
    #pragma unroll
    for (int r = 0; r < 4; ++r) {
        rad_r[r] = __shfl(radial_reg, 4 * (quad * 4 + r), 64);
        ea_r[r]  = __shfl(ea_reg,     4 * (quad * 4 + r), 64);
    }
    #pragma unroll
    for (int nt = 0; nt < 8; ++nt) {
        float w256 = eW1[256 * H + nt * 16 + l15];
        float w257 = eW1[257 * H + nt * 16 + l15];
        #pragma unroll
        for (int r = 0; r < 4; ++r)
            acc[nt][r] += rad_r[r] * w256 + ea_r[r] * w257;
    }

    // ---- epilogue 1 -> A2 (ushort offset 0, octs 0..15) ----
    ln_silu_store(acc, eb1, eg1, ebe1, A, l15, quad);

    // ---- GEMM2: [16x128] @ eW2t ----
    f32x4 acc2[8];
    #pragma unroll
    for (int nt = 0; nt < 8; ++nt) acc2[nt] = (f32x4){0.f, 0.f, 0.f, 0.f};
    for (int kb = 0; kb < 4; ++kb) {
        bf16x8 af = *(const bf16x8*)&A[((kb * 4 + quad) * 16 + l15) * 8];
        const unsigned short* bp = eW2t + (size_t)l15 * H + kb * 32 + quad * 8;
        #pragma unroll
        for (int nt = 0; nt < 8; ++nt) {
            bf16x8 bf = *(const bf16x8*)(bp + (size_t)nt * 16 * H);
            acc2[nt] = __builtin_amdgcn_mfma_f32_16x16x32_bf16(af, bf, acc2[nt], 0, 0, 0);
        }
    }

    // ---- epilogue 2 = edge_feat -> A3 (ushort offset 2048, octs 16..31); agg atomics ----
    ln_silu_store(acc2, eb2, eg2, ebe2, A + 2048, l15, quad);

    int rowm[4];
    #pragma unroll
    for (int r = 0; r < 4; ++r) rowm[r] = __shfl(row, 4 * (quad * 4 + r), 64);
    #pragma unroll
    for (int nt = 0; nt < 8; ++nt) {
        #pragma unroll
        for (int r = 0; r < 4; ++r) {
            int geh = ge0 + quad * 4 + r;
            if (geh < E)
                atomicAdd(&agg[(size_t)rowm[r] * H + nt * 16 + l15], acc2[nt][r]);
        }
    }

    // ---- GEMM3: edge_feat @ cW1t ----
    #pragma unroll
    for (int nt = 0; nt < 8; ++nt) acc[nt] = (f32x4){0.f, 0.f, 0.f, 0.f};
    for (int kb = 0; kb < 4; ++kb) {
        bf16x8 af = *(const bf16x8*)&A[2048 + ((kb * 4 + quad) * 16 + l15) * 8];
        const unsigned short* bp = cW1t + (size_t)l15 * H + kb * 32 + quad * 8;
        #pragma unroll
        for (int nt = 0; nt < 8; ++nt) {
            bf16x8 bf = *(const bf16x8*)(bp + (size_t)nt * 16 * H);
            acc[nt] = __builtin_amdgcn_mfma_f32_16x16x32_bf16(af, bf, acc[nt], 0, 0, 0);
        }
    }

    // ---- epilogue 3: bias + LN + SiLU, dot cW2 -> cm; coord atomics ----
    {
        float s[4] = {0, 0, 0, 0}, ss[4] = {0, 0, 0, 0};
        #pragma unroll
        for (int nt = 0; nt < 8; ++nt) {
            float b = cb1[nt * 16 + l15];
            #pragma unroll
            for (int r = 0; r < 4; ++r) {
                float x = acc[nt][r] + b;
                acc[nt][r] = x;
                s[r] += x; ss[r] += x * x;
            }
        }
        #pragma unroll
        for (int m = 1; m <= 8; m <<= 1) {
            #pragma unroll
            for (int r = 0; r < 4; ++r) {
                s[r]  += __shfl_xor(s[r],  m, 64);
                ss[r] += __shfl_xor(ss[r], m, 64);
            }
        }
        float cm[4] = {0, 0, 0, 0};
        #pragma unroll
        for (int r = 0; r < 4; ++r) {
            float mu   = s[r] * (1.0f / 128.0f);
            float var  = ss[r] * (1.0f / 128.0f) - mu * mu;
            s[r]  = mu;
            ss[r] = rsqrtf(var + 1e-5f);
        }
        #pragma unroll
        for (int nt = 0; nt < 8; ++nt) {
            float g  = cg1[nt * 16 + l15], be = cbe1[nt * 16 + l15];
            float w2 = cW2[nt * 16 + l15];
            #pragma unroll
            for (int r = 0; r < 4; ++r) {
                float p = silu_f((acc[nt][r] - s[r]) * ss[r] * g + be);
                cm[r] += p * w2;
            }
        }
        #pragma unroll
        for (int m = 1; m <= 8; m <<= 1) {
            #pragma unroll
            for (int r = 0; r < 4; ++r) cm[r] += __shfl_xor(cm[r], m, 64);
        }
        #pragma unroll
        for (int r = 0; r < 4; ++r) {
            float cdxr = __shfl(cdx, 4 * (quad * 4 + r), 64);
            float cdyr = __shfl(cdy, 4 * (quad * 4 + r), 64);
            float cdzr = __shfl(cdz, 4 * (quad * 4 + r), 64);
            float comp = (l15 == 0) ? cdxr : ((l15 == 1) ? cdyr : cdzr);
            int geh = ge0 + quad * 4 + r;
            if (l15 < 3 && geh < E)
                atomicAdd(&coord_out[(size_t)rowm[r] * 3 + l15], comp * cm[r]);
        }
    }
}

// -------------------- node kernel: 1 wave, 16 nodes, MFMA, barrier-free ------------
__global__ __launch_bounds__(64, 4) void node_kernel(
    const unsigned short* __restrict__ hb, const float* __restrict__ h,
    const float* __restrict__ agg,
    const unsigned short* __restrict__ nW1t,
    const float* __restrict__ nb1, const float* __restrict__ ng1, const float* __restrict__ nbe1,
    const unsigned short* __restrict__ nW2t, const float* __restrict__ nb2,
    float* __restrict__ out, int N)
{
    __shared__ unsigned short A[32 * 16 * 8];   // 8192 B

    const int lane = threadIdx.x;
    const int l15 = lane & 15, quad = lane >> 4;
    const int m = lane >> 2, part = lane & 3;
    const int gn0 = blockIdx.x * 16;
    int gn  = gn0 + m;
    int gnc = (gn < N) ? gn : (N - 1);

    // ---- stage [h_bf16 | bf16(agg)] ----
    if (part < 2) {
        const unsigned short* src = hb + (size_t)gnc * H + part * 64;
        const int oct0 = part * 8;
        #pragma unroll
        for (int c = 0; c < 8; ++c)
            *(uint4*)&A[((oct0 + c) * 16 + m) * 8] = *(const uint4*)(src + c * 8);
    } else {
        const float* src = agg + (size_t)gnc * H + (part & 1) * 64;
        const int oct0 = 16 + (part & 1) * 8;
        #pragma unroll
        for (int c = 0; c < 8; ++c) {
            float4 f0 = ((const float4*)src)[2 * c];
            float4 f1 = ((const float4*)src)[2 * c + 1];
            union { bf16x8 v; unsigned short u[8]; } pk;
            pk.u[0] = f2bf(f0.x); pk.u[1] = f2bf(f0.y); pk.u[2] = f2bf(f0.z); pk.u[3] = f2bf(f0.w);
            pk.u[4] = f2bf(f1.x); pk.u[5] = f2bf(f1.y); pk.u[6] = f2bf(f1.z); pk.u[7] = f2bf(f1.w);
            *(bf16x8*)&A[((oct0 + c) * 16 + m) * 8] = pk.v;
        }
    }

    f32x4 acc[8];
    #pragma unroll
    for (int nt = 0; nt < 8; ++nt) acc[nt] = (f32x4){0.f, 0.f, 0.f, 0.f};

    // ---- GEMM1: [16x256] @ nW1t[128][256] ----
    for (int kb = 0; kb < 8; ++kb) {
        bf16x8 af = *(const bf16x8*)&A[((kb * 4 + quad) * 16 + l15) * 8];
        const unsigned short* bp = nW1t + (size_t)l15 * KN + kb * 32 + quad * 8;
        #pragma unroll
        for (int nt = 0; nt < 8; ++nt) {
            bf16x8 bf = *(const bf16x8*)(bp + (size_t)nt * 16 * KN);
            acc[nt] = __builtin_amdgcn_mfma_f32_16x16x32_bf16(af, bf, acc[nt], 0, 0, 0);
        }
    }

    // ---- epilogue: bias + LN + SiLU -> A2 (octs 0..15) ----
    ln_silu_store(acc, nb1, ng1, nbe1, A, l15, quad);

    // ---- GEMM2: @ nW2t ----
    f32x4 acc2[8];
    #pragma unroll
    for (int nt = 0; nt < 8; ++nt) acc2[nt] = (f32x4){0.f, 0.f, 0.f, 0.f};
    for (int kb = 0; kb < 4; ++kb) {
        bf16x8 af = *(const bf16x8*)&A[((kb * 4 + quad) * 16 + l15) * 8];
        const unsigned short* bp = nW2t + (size_t)l15 * H + kb * 32 + quad * 8;
        #pragma unroll
        for (int nt = 0; nt < 8; ++nt) {
            bf16x8 bf = *(const bf16x8*)(bp + (size_t)nt * 16 * H);
            acc2[nt] = __builtin_amdgcn_mfma_f32_16x16x32_bf16(af, bf, acc2[nt], 0, 0, 0);
        }
    }

    // ---- out = h + acc2 + b ----
    #pragma unroll
    for (int nt = 0; nt < 8; ++nt) {
        float b = nb2[nt * 16 + l15];
        #pragma unroll
        for (int r = 0; r < 4; ++r) {
            int gnr = gn0 + quad * 4 + r;
            if (gnr < N) {
                size_t idx = (size_t)gnr * H + nt * 16 + l15;
                out[idx] = acc2[nt][r] + b + h[idx];
            }
        }
    }
}

// -------------------- launch --------------------
extern "C" void kernel_launch(void* const* d_in, const int* in_sizes, int n_in,
                              void* d_out, int out_size, void* d_ws, size_t ws_size,
                              hipStream_t stream) {
    const float* h     = (const float*)d_in[0];
    const int*   ei    = (const int*)d_in[1];
    const float* coord = (const float*)d_in[2];
    const float* eattr = (const float*)d_in[3];
    const float* eW1   = (const float*)d_in[4];
    const float* eb1   = (const float*)d_in[5];
    const float* eg1   = (const float*)d_in[6];
    const float* ebe1  = (const float*)d_in[7];
    const float* eW2   = (const float*)d_in[8];
    const float* eb2   = (const float*)d_in[9];
    const float* eg2   = (const float*)d_in[10];
    const float* ebe2  = (const float*)d_in[11];
    const float* nW1   = (const float*)d_in[12];
    const float* nb1   = (const float*)d_in[13];
    const float* ng1   = (const float*)d_in[14];
    const float* nbe1  = (const float*)d_in[15];
    const float* nW2   = (const float*)d_in[16];
    const float* nb2   = (const float*)d_in[17];
    const float* cW1   = (const float*)d_in[18];
    const float* cb1   = (const float*)d_in[19];
    const float* cg1   = (const float*)d_in[20];
    const float* cbe1  = (const float*)d_in[21];
    const float* cW2   = (const float*)d_in[22];

    const int N = in_sizes[0] / H;
    const int E = in_sizes[1] / 2;

    float* out       = (float*)d_out;
    float* coord_out = out + (size_t)N * H;

    // ---- workspace layout ----
    char* ws = (char*)d_ws;
    size_t o = 0;
    float* agg = (float*)(ws + o);              o += (size_t)N * H * 4;
    unsigned short* hb   = (unsigned short*)(ws + o); o += (size_t)N * H * 2;
    unsigned short* eW1t = (unsigned short*)(ws + o); o += (size_t)H * KE * 2;
    unsigned short* eW2t = (unsigned short*)(ws + o); o += (size_t)H * H * 2;
    unsigned short* cW1t = (unsigned short*)(ws + o); o += (size_t)H * H * 2;
    unsigned short* nW1t = (unsigned short*)(ws + o); o += (size_t)H * KN * 2;
    unsigned short* nW2t = (unsigned short*)(ws + o); o += (size_t)H * H * 2;

    hipMemsetAsync(agg, 0, (size_t)N * H * sizeof(float), stream);
    hipMemcpyAsync(coord_out, coord, (size_t)N * 3 * sizeof(float),
                   hipMemcpyDeviceToDevice, stream);

    prep_h<<<(N * H + 255) / 256, 256, 0, stream>>>(h, hb, N * H);
    prep_wt<<<dim3(1, H), 256, 0, stream>>>(eW1, eW1t, KE);   // rows 0..255 of 258
    prep_wt<<<dim3(1, H), 256, 0, stream>>>(eW2, eW2t, H);
    prep_wt<<<dim3(1, H), 256, 0, stream>>>(cW1, cW1t, H);
    prep_wt<<<dim3(1, H), 256, 0, stream>>>(nW1, nW1t, KN);
    prep_wt<<<dim3(1, H), 256, 0, stream>>>(nW2, nW2t, H);

    edge_kernel<<<(E + 15) / 16, 64, 0, stream>>>(
        hb, ei, coord, eattr,
        eW1t, eW1, eb1, eg1, ebe1,
        eW2t, eb2, eg2, ebe2,
        cW1t, cb1, cg1, cbe1, cW2,
        agg, coord_out, E);

    node_kernel<<<(N + 15) / 16, 64, 0, stream>>>(
        hb, h, agg, nW1t, nb1, ng1, nbe1, nW2t, nb2, out, N);
}

// Round 5
// 449.489 us; speedup vs baseline: 1.8467x; 1.4224x over previous
//
#include <hip/hip_runtime.h>
#include <math.h>

#define H 128
#define KE 256      // MFMA K for edge GEMM1 (k=256,257 via fp32 rank-1 update)
#define KN 256      // node GEMM1 K (2H)

typedef __attribute__((ext_vector_type(8))) short bf16x8;
typedef __attribute__((ext_vector_type(4))) float f32x4;

__device__ __forceinline__ float silu_f(float x) { return x / (1.0f + __expf(-x)); }

__device__ __forceinline__ unsigned short f2bf(float f) {
    unsigned int u = __float_as_uint(f);
    unsigned int r = u + 0x7FFFu + ((u >> 16) & 1u);
    return (unsigned short)(r >> 16);
}

// -------------------- prep: fp32 -> bf16 (h, agg) --------------------
__global__ void prep_h(const float* __restrict__ x, unsigned short* __restrict__ y, int n) {
    int i = blockIdx.x * 256 + threadIdx.x;
    if (i < n) y[i] = f2bf(x[i]);
}

// ---- prep: W[K][128] fp32 -> fragment-linear Wf[(kb*8+nt)*64+lane][8] bf16 ----
// lane=(quad,l15): fragment = W[k=kb*32+quad*8+j][n=nt*16+l15], j=0..7
__global__ void prep_wf(const float* __restrict__ W, unsigned short* __restrict__ Wf) {
    int f = blockIdx.x * 64 + threadIdx.x;   // one fragment per thread
    int kb = f >> 9;
    int rem = f & 511;
    int nt = rem >> 6, lane = rem & 63;
    int quad = lane >> 4, l15 = lane & 15;
    int n = nt * 16 + l15, k0 = kb * 32 + quad * 8;
    union { bf16x8 v; unsigned short u[8]; } pk;
    #pragma unroll
    for (int j = 0; j < 8; ++j) pk.u[j] = f2bf(W[(size_t)(k0 + j) * H + n]);
    *(bf16x8*)&Wf[(size_t)f * 8] = pk.v;
}

// ---- shared epilogue: bias + LN + SiLU; silu result left in acc, bf16 copy in LDS ----
__device__ __forceinline__ void ln_silu_store(
    f32x4* acc, const float* __restrict__ bias, const float* __restrict__ g,
    const float* __restrict__ be, unsigned short* dstA, int l15, int quad)
{
    float s[4] = {0, 0, 0, 0}, ss[4] = {0, 0, 0, 0};
    #pragma unroll
    for (int nt = 0; nt < 8; ++nt) {
        float b = bias[nt * 16 + l15];
        #pragma unroll
        for (int r = 0; r < 4; ++r) {
            float x = acc[nt][r] + b;
            acc[nt][r] = x;
            s[r] += x; ss[r] += x * x;
        }
    }
    #pragma unroll
    for (int m = 1; m <= 8; m <<= 1) {
        #pragma unroll
        for (int r = 0; r < 4; ++r) {
            s[r]  += __shfl_xor(s[r],  m, 64);
            ss[r] += __shfl_xor(ss[r], m, 64);
        }
    }
    #pragma unroll
    for (int r = 0; r < 4; ++r) {
        float mu  = s[r] * (1.0f / 128.0f);
        float var = ss[r] * (1.0f / 128.0f) - mu * mu;
        s[r]  = mu;
        ss[r] = rsqrtf(var + 1e-5f);
    }
    #pragma unroll
    for (int nt = 0; nt < 8; ++nt) {
        float gg = g[nt * 16 + l15], bb = be[nt * 16 + l15];
        int oct = nt * 2 + (l15 >> 3), j = l15 & 7;
        #pragma unroll
        for (int r = 0; r < 4; ++r) {
            float y = silu_f((acc[nt][r] - s[r]) * ss[r] * gg + bb);
            acc[nt][r] = y;
            dstA[(oct * 16 + quad * 4 + r) * 8 + j] = f2bf(y);
        }
    }
}

// -------------------- edge kernel: 1 wave, 32 edges (2 M-tiles), barrier-free ------
__global__ __launch_bounds__(64) void edge_kernel(
    const unsigned short* __restrict__ hb, const int* __restrict__ ei,
    const float* __restrict__ coord, const float* __restrict__ eattr,
    const unsigned short* __restrict__ eW1f, const float* __restrict__ eW1,
    const float* __restrict__ eb1, const float* __restrict__ eg1, const float* __restrict__ ebe1,
    const unsigned short* __restrict__ eW2f,
    const float* __restrict__ eb2, const float* __restrict__ eg2, const float* __restrict__ ebe2,
    const unsigned short* __restrict__ cW1f,
    const float* __restrict__ cb1, const float* __restrict__ cg1, const float* __restrict__ cbe1,
    const float* __restrict__ cW2,
    float* __restrict__ agg, float* __restrict__ coord_out, int E)
{
    __shared__ unsigned short A2[2][2048];   // 4 KB per tile (C->A transpose buffer)

    const int lane = threadIdx.x;
    const int l15 = lane & 15, quad = lane >> 4;
    const int ge0 = blockIdx.x * 32;

    // per-lane edge (lane&31): indices + geometry
    int el = ge0 + (lane & 31);
    int elc = (el < E) ? el : (E - 1);
    int rowl = ei[elc], coll = ei[E + elc];
    float dx = coord[rowl * 3 + 0] - coord[coll * 3 + 0];
    float dy = coord[rowl * 3 + 1] - coord[coll * 3 + 1];
    float dz = coord[rowl * 3 + 2] - coord[coll * 3 + 2];
    float radial = dx * dx + dy * dy + dz * dz;
    float inv = 1.0f / (sqrtf(radial + 1e-8f) + 1.0f);
    float cdx = dx * inv, cdy = dy * inv, cdz = dz * inv;
    float ea = eattr[elc];

    // fragment-row indices for the two tiles
    int row_t0 = __shfl(rowl, l15, 64),      col_t0 = __shfl(coll, l15, 64);
    int row_t1 = __shfl(rowl, l15 + 16, 64), col_t1 = __shfl(coll, l15 + 16, 64);

    const unsigned short* a0r = hb + (size_t)row_t0 * H;
    const unsigned short* a0c = hb + (size_t)col_t0 * H;
    const unsigned short* a1r = hb + (size_t)row_t1 * H;
    const unsigned short* a1c = hb + (size_t)col_t1 * H;

    f32x4 accA[8], accB[8];
    #pragma unroll
    for (int nt = 0; nt < 8; ++nt) {
        accA[nt] = (f32x4){0.f, 0.f, 0.f, 0.f};
        accB[nt] = (f32x4){0.f, 0.f, 0.f, 0.f};
    }

    // ---- GEMM1: [32x256] @ eW1f, A direct from global ----
    for (int kb = 0; kb < 8; ++kb) {
        int ko = (kb & 3) * 32 + quad * 8;
        bf16x8 afA = *(const bf16x8*)(((kb < 4) ? a0r : a0c) + ko);
        bf16x8 afB = *(const bf16x8*)(((kb < 4) ? a1r : a1c) + ko);
        const unsigned short* bp = eW1f + ((size_t)kb * 8) * 512 + (size_t)lane * 8;
        #pragma unroll
        for (int nt = 0; nt < 8; ++nt) {
            bf16x8 bf = *(const bf16x8*)(bp + (size_t)nt * 512);
            accA[nt] = __builtin_amdgcn_mfma_f32_16x16x32_bf16(afA, bf, accA[nt], 0, 0, 0);
            accB[nt] = __builtin_amdgcn_mfma_f32_16x16x32_bf16(afB, bf, accB[nt], 0, 0, 0);
        }
    }

    // ---- rank-1 fp32 update: k=256 (radial), k=257 (eattr) ----
    {
        float radA[4], eaA[4], radB[4], eaB[4];
        #pragma unroll
        for (int r = 0; r < 4; ++r) {
            radA[r] = __shfl(radial, quad * 4 + r, 64);
            eaA[r]  = __shfl(ea,     quad * 4 + r, 64);
            radB[r] = __shfl(radial, 16 + quad * 4 + r, 64);
            eaB[r]  = __shfl(ea,     16 + quad * 4 + r, 64);
        }
        #pragma unroll
        for (int nt = 0; nt < 8; ++nt) {
            float w256 = eW1[256 * H + nt * 16 + l15];
            float w257 = eW1[257 * H + nt * 16 + l15];
            #pragma unroll
            for (int r = 0; r < 4; ++r) {
                accA[nt][r] += radA[r] * w256 + eaA[r] * w257;
                accB[nt][r] += radB[r] * w256 + eaB[r] * w257;
            }
        }
    }

    // ---- epilogue 1 -> A2 per tile ----
    ln_silu_store(accA, eb1, eg1, ebe1, &A2[0][0], l15, quad);
    ln_silu_store(accB, eb1, eg1, ebe1, &A2[1][0], l15, quad);

    // ---- GEMM2: @ eW2f ----
    f32x4 ac2A[8], ac2B[8];
    #pragma unroll
    for (int nt = 0; nt < 8; ++nt) {
        ac2A[nt] = (f32x4){0.f, 0.f, 0.f, 0.f};
        ac2B[nt] = (f32x4){0.f, 0.f, 0.f, 0.f};
    }
    for (int kb = 0; kb < 4; ++kb) {
        bf16x8 afA = *(const bf16x8*)&A2[0][((kb * 4 + quad) * 16 + l15) * 8];
        bf16x8 afB = *(const bf16x8*)&A2[1][((kb * 4 + quad) * 16 + l15) * 8];
        const unsigned short* bp = eW2f + ((size_t)kb * 8) * 512 + (size_t)lane * 8;
        #pragma unroll
        for (int nt = 0; nt < 8; ++nt) {
            bf16x8 bf = *(const bf16x8*)(bp + (size_t)nt * 512);
            ac2A[nt] = __builtin_amdgcn_mfma_f32_16x16x32_bf16(afA, bf, ac2A[nt], 0, 0, 0);
            ac2B[nt] = __builtin_amdgcn_mfma_f32_16x16x32_bf16(afB, bf, ac2B[nt], 0, 0, 0);
        }
    }

    // ---- epilogue 2 = edge_feat -> A2 (aliased); agg atomics ----
    ln_silu_store(ac2A, eb2, eg2, ebe2, &A2[0][0], l15, quad);
    ln_silu_store(ac2B, eb2, eg2, ebe2, &A2[1][0], l15, quad);

    int rowA[4], rowB[4];
    #pragma unroll
    for (int r = 0; r < 4; ++r) {
        rowA[r] = __shfl(rowl, quad * 4 + r, 64);
        rowB[r] = __shfl(rowl, 16 + quad * 4 + r, 64);
    }
    #pragma unroll
    for (int nt = 0; nt < 8; ++nt) {
        #pragma unroll
        for (int r = 0; r < 4; ++r) {
            int geA = ge0 + quad * 4 + r;
            int geB = geA + 16;
            if (geA < E) atomicAdd(&agg[(size_t)rowA[r] * H + nt * 16 + l15], ac2A[nt][r]);
            if (geB < E) atomicAdd(&agg[(size_t)rowB[r] * H + nt * 16 + l15], ac2B[nt][r]);
        }
    }

    // ---- GEMM3: edge_feat @ cW1f ----
    #pragma unroll
    for (int nt = 0; nt < 8; ++nt) {
        accA[nt] = (f32x4){0.f, 0.f, 0.f, 0.f};
        accB[nt] = (f32x4){0.f, 0.f, 0.f, 0.f};
    }
    for (int kb = 0; kb < 4; ++kb) {
        bf16x8 afA = *(const bf16x8*)&A2[0][((kb * 4 + quad) * 16 + l15) * 8];
        bf16x8 afB = *(const bf16x8*)&A2[1][((kb * 4 + quad) * 16 + l15) * 8];
        const unsigned short* bp = cW1f + ((size_t)kb * 8) * 512 + (size_t)lane * 8;
        #pragma unroll
        for (int nt = 0; nt < 8; ++nt) {
            bf16x8 bf = *(const bf16x8*)(bp + (size_t)nt * 512);
            accA[nt] = __builtin_amdgcn_mfma_f32_16x16x32_bf16(afA, bf, accA[nt], 0, 0, 0);
            accB[nt] = __builtin_amdgcn_mfma_f32_16x16x32_bf16(afB, bf, accB[nt], 0, 0, 0);
        }
    }

    // ---- epilogue 3: per tile LN+SiLU, dot cW2 -> cm; coord atomics ----
    #pragma unroll
    for (int tile = 0; tile < 2; ++tile) {
        f32x4* acc = tile ? accB : accA;
        float s[4] = {0, 0, 0, 0}, ss[4] = {0, 0, 0, 0};
        #pragma unroll
        for (int nt = 0; nt < 8; ++nt) {
            float b = cb1[nt * 16 + l15];
            #pragma unroll
            for (int r = 0; r < 4; ++r) {
                float x = acc[nt][r] + b;
                acc[nt][r] = x;
                s[r] += x; ss[r] += x * x;
            }
        }
        #pragma unroll
        for (int m = 1; m <= 8; m <<= 1) {
            #pragma unroll
            for (int r = 0; r < 4; ++r) {
                s[r]  += __shfl_xor(s[r],  m, 64);
                ss[r] += __shfl_xor(ss[r], m, 64);
            }
        }
        float cm[4] = {0, 0, 0, 0};
        #pragma unroll
        for (int r = 0; r < 4; ++r) {
            float mu  = s[r] * (1.0f / 128.0f);
            float var = ss[r] * (1.0f / 128.0f) - mu * mu;
            s[r]  = mu;
            ss[r] = rsqrtf(var + 1e-5f);
        }
        #pragma unroll
        for (int nt = 0; nt < 8; ++nt) {
            float g  = cg1[nt * 16 + l15], be = cbe1[nt * 16 + l15];
            float w2 = cW2[nt * 16 + l15];
            #pragma unroll
            for (int r = 0; r < 4; ++r) {
                float p = silu_f((acc[nt][r] - s[r]) * ss[r] * g + be);
                cm[r] += p * w2;
            }
        }
        #pragma unroll
        for (int m = 1; m <= 8; m <<= 1) {
            #pragma unroll
            for (int r = 0; r < 4; ++r) cm[r] += __shfl_xor(cm[r], m, 64);
        }
        #pragma unroll
        for (int r = 0; r < 4; ++r) {
            int src = tile * 16 + quad * 4 + r;
            float cdxr = __shfl(cdx, src, 64);
            float cdyr = __shfl(cdy, src, 64);
            float cdzr = __shfl(cdz, src, 64);
            int rw = __shfl(rowl, src, 64);
            float comp = (l15 == 0) ? cdxr : ((l15 == 1) ? cdyr : cdzr);
            int geh = ge0 + src;
            if (l15 < 3 && geh < E)
                atomicAdd(&coord_out[(size_t)rw * 3 + l15], comp * cm[r]);
        }
    }
}

// -------------------- node kernel: 1 wave, 32 nodes (2 M-tiles) --------------------
__global__ __launch_bounds__(64) void node_kernel(
    const unsigned short* __restrict__ hb, const float* __restrict__ h,
    const unsigned short* __restrict__ aggb,
    const unsigned short* __restrict__ nW1f,
    const float* __restrict__ nb1, const float* __restrict__ ng1, const float* __restrict__ nbe1,
    const unsigned short* __restrict__ nW2f, const float* __restrict__ nb2,
    float* __restrict__ out, int N)
{
    __shared__ unsigned short A2[2][2048];

    const int lane = threadIdx.x;
    const int l15 = lane & 15, quad = lane >> 4;
    const int gn0 = blockIdx.x * 32;

    int n_t0 = gn0 + l15;      if (n_t0 >= N) n_t0 = N - 1;
    int n_t1 = gn0 + 16 + l15; if (n_t1 >= N) n_t1 = N - 1;

    const unsigned short* a0h = hb   + (size_t)n_t0 * H;
    const unsigned short* a0a = aggb + (size_t)n_t0 * H;
    const unsigned short* a1h = hb   + (size_t)n_t1 * H;
    const unsigned short* a1a = aggb + (size_t)n_t1 * H;

    f32x4 accA[8], accB[8];
    #pragma unroll
    for (int nt = 0; nt < 8; ++nt) {
        accA[nt] = (f32x4){0.f, 0.f, 0.f, 0.f};
        accB[nt] = (f32x4){0.f, 0.f, 0.f, 0.f};
    }

    // ---- GEMM1: [32x256] @ nW1f ----
    for (int kb = 0; kb < 8; ++kb) {
        int ko = (kb & 3) * 32 + quad * 8;
        bf16x8 afA = *(const bf16x8*)(((kb < 4) ? a0h : a0a) + ko);
        bf16x8 afB = *(const bf16x8*)(((kb < 4) ? a1h : a1a) + ko);
        const unsigned short* bp = nW1f + ((size_t)kb * 8) * 512 + (size_t)lane * 8;
        #pragma unroll
        for (int nt = 0; nt < 8; ++nt) {
            bf16x8 bf = *(const bf16x8*)(bp + (size_t)nt * 512);
            accA[nt] = __builtin_amdgcn_mfma_f32_16x16x32_bf16(afA, bf, accA[nt], 0, 0, 0);
            accB[nt] = __builtin_amdgcn_mfma_f32_16x16x32_bf16(afB, bf, accB[nt], 0, 0, 0);
        }
    }

    ln_silu_store(accA, nb1, ng1, nbe1, &A2[0][0], l15, quad);
    ln_silu_store(accB, nb1, ng1, nbe1, &A2[1][0], l15, quad);

    // ---- GEMM2: @ nW2f ----
    f32x4 ac2A[8], ac2B[8];
    #pragma unroll
    for (int nt = 0; nt < 8; ++nt) {
        ac2A[nt] = (f32x4){0.f, 0.f, 0.f, 0.f};
        ac2B[nt] = (f32x4){0.f, 0.f, 0.f, 0.f};
    }
    for (int kb = 0; kb < 4; ++kb) {
        bf16x8 afA = *(const bf16x8*)&A2[0][((kb * 4 + quad) * 16 + l15) * 8];
        bf16x8 afB = *(const bf16x8*)&A2[1][((kb * 4 + quad) * 16 + l15) * 8];
        const unsigned short* bp = nW2f + ((size_t)kb * 8) * 512 + (size_t)lane * 8;
        #pragma unroll
        for (int nt = 0; nt < 8; ++nt) {
            bf16x8 bf = *(const bf16x8*)(bp + (size_t)nt * 512);
            ac2A[nt] = __builtin_amdgcn_mfma_f32_16x16x32_bf16(afA, bf, ac2A[nt], 0, 0, 0);
            ac2B[nt] = __builtin_amdgcn_mfma_f32_16x16x32_bf16(afB, bf, ac2B[nt], 0, 0, 0);
        }
    }

    // ---- out = h + acc2 + b ----
    #pragma unroll
    for (int nt = 0; nt < 8; ++nt) {
        float b = nb2[nt * 16 + l15];
        #pragma unroll
        for (int r = 0; r < 4; ++r) {
            int gA = gn0 + quad * 4 + r;
            int gB = gA + 16;
            if (gA < N) {
                size_t idx = (size_t)gA * H + nt * 16 + l15;
                out[idx] = ac2A[nt][r] + b + h[idx];
            }
            if (gB < N) {
                size_t idx = (size_t)gB * H + nt * 16 + l15;
                out[idx] = ac2B[nt][r] + b + h[idx];
            }
        }
    }
}

// -------------------- launch --------------------
extern "C" void kernel_launch(void* const* d_in, const int* in_sizes, int n_in,
                              void* d_out, int out_size, void* d_ws, size_t ws_size,
                              hipStream_t stream) {
    const float* h     = (const float*)d_in[0];
    const int*   ei    = (const int*)d_in[1];
    const float* coord = (const float*)d_in[2];
    const float* eattr = (const float*)d_in[3];
    const float* eW1   = (const float*)d_in[4];
    const float* eb1   = (const float*)d_in[5];
    const float* eg1   = (const float*)d_in[6];
    const float* ebe1  = (const float*)d_in[7];
    const float* eW2   = (const float*)d_in[8];
    const float* eb2   = (const float*)d_in[9];
    const float* eg2   = (const float*)d_in[10];
    const float* ebe2  = (const float*)d_in[11];
    const float* nW1   = (const float*)d_in[12];
    const float* nb1   = (const float*)d_in[13];
    const float* ng1   = (const float*)d_in[14];
    const float* nbe1  = (const float*)d_in[15];
    const float* nW2   = (const float*)d_in[16];
    const float* nb2   = (const float*)d_in[17];
    const float* cW1   = (const float*)d_in[18];
    const float* cb1   = (const float*)d_in[19];
    const float* cg1   = (const float*)d_in[20];
    const float* cbe1  = (const float*)d_in[21];
    const float* cW2   = (const float*)d_in[22];

    const int N = in_sizes[0] / H;
    const int E = in_sizes[1] / 2;

    float* out       = (float*)d_out;
    float* coord_out = out + (size_t)N * H;

    // ---- workspace layout ----
    char* ws = (char*)d_ws;
    size_t o = 0;
    float* agg = (float*)(ws + o);                    o += (size_t)N * H * 4;
    unsigned short* hb   = (unsigned short*)(ws + o); o += (size_t)N * H * 2;
    unsigned short* aggb = (unsigned short*)(ws + o); o += (size_t)N * H * 2;
    unsigned short* eW1f = (unsigned short*)(ws + o); o += (size_t)H * KE * 2;
    unsigned short* eW2f = (unsigned short*)(ws + o); o += (size_t)H * H * 2;
    unsigned short* cW1f = (unsigned short*)(ws + o); o += (size_t)H * H * 2;
    unsigned short* nW1f = (unsigned short*)(ws + o); o += (size_t)H * KN * 2;
    unsigned short* nW2f = (unsigned short*)(ws + o); o += (size_t)H * H * 2;

    hipMemsetAsync(agg, 0, (size_t)N * H * sizeof(float), stream);
    hipMemcpyAsync(coord_out, coord, (size_t)N * 3 * sizeof(float),
                   hipMemcpyDeviceToDevice, stream);

    prep_h<<<(N * H + 255) / 256, 256, 0, stream>>>(h, hb, N * H);
    prep_wf<<<8 * 8, 64, 0, stream>>>(eW1, eW1f);   // KB=8 (rows 0..255)
    prep_wf<<<4 * 8, 64, 0, stream>>>(eW2, eW2f);   // KB=4
    prep_wf<<<4 * 8, 64, 0, stream>>>(cW1, cW1f);
    prep_wf<<<8 * 8, 64, 0, stream>>>(nW1, nW1f);
    prep_wf<<<4 * 8, 64, 0, stream>>>(nW2, nW2f);

    edge_kernel<<<(E + 31) / 32, 64, 0, stream>>>(
        hb, ei, coord, eattr,
        eW1f, eW1, eb1, eg1, ebe1,
        eW2f, eb2, eg2, ebe2,
        cW1f, cb1, cg1, cbe1, cW2,
        agg, coord_out, E);

    prep_h<<<(N * H + 255) / 256, 256, 0, stream>>>(agg, aggb, N * H);

    node_kernel<<<(N + 31) / 32, 64, 0, stream>>>(
        hb, h, aggb, nW1f, nb1, ng1, nbe1, nW2f, nb2, out, N);
}